// Round 6
// baseline (689.999 us; speedup 1.0000x reference)
//
#include <hip/hip_runtime.h>

#define E_TOTAL 800000
#define N_TOTAL 50000
#define NBINS   50176   // 1024*49, padded

typedef __attribute__((ext_vector_type(8))) short short8;
typedef __attribute__((ext_vector_type(4))) float floatx4;

__device__ __forceinline__ unsigned short f2bf(float f) {
    union { float f; unsigned u; } x; x.f = f;
    unsigned r = x.u + 0x7fff + ((x.u >> 16) & 1);   // RNE
    return (unsigned short)(r >> 16);
}

// ---------------- fused prep: weight transpose + mi zero + h->bf16 + hist zero ----------------
__global__ __launch_bounds__(256)
void prep(const float* __restrict__ We1, const float* __restrict__ We2,
          const float* __restrict__ Wh1, const float* __restrict__ Wh2,
          unsigned short* __restrict__ W1t, unsigned short* __restrict__ W2t,
          unsigned short* __restrict__ Wh1t, unsigned short* __restrict__ Wh2t,
          const float* __restrict__ h, unsigned short* __restrict__ hbf, int do_full,
          float* __restrict__ mi, int* __restrict__ hist)
{
    const int b = blockIdx.x;
    const int tid = threadIdx.x;
    if (b < 400) {
        int t = b * 256 + tid;
        if (t < 36864) {
            W1t[(t & 127) * 288 + (t >> 7)] = f2bf(We1[t]);
        } else if (t < 53248) {
            t -= 36864;
            W2t[(t & 127) * 128 + (t >> 7)] = f2bf(We2[t]);
        } else if (t < 86016) {
            t -= 53248;
            Wh1t[(t & 127) * 256 + (t >> 7)] = f2bf(Wh1[t]);
        } else if (t < 102400) {
            t -= 86016;
            Wh2t[(t & 127) * 128 + (t >> 7)] = f2bf(Wh2[t]);
        }
    } else if (b < 6650) {
        const int t = (b - 400) * 256 + tid;
        ((float4*)mi)[t] = make_float4(0.f, 0.f, 0.f, 0.f);
    } else if (b < 9775) {
        if (do_full) {
            const int t = (b - 6650) * 256 + tid;
            const float4* h4 = (const float4*)h;
            float4 a = h4[(size_t)t * 2];
            float4 c = h4[(size_t)t * 2 + 1];
            short8 v = { (short)f2bf(a.x), (short)f2bf(a.y), (short)f2bf(a.z), (short)f2bf(a.w),
                         (short)f2bf(c.x), (short)f2bf(c.y), (short)f2bf(c.z), (short)f2bf(c.w) };
            *(short8*)(&hbf[(size_t)t * 8]) = v;
        }
    } else {
        if (do_full) hist[(b - 9775) * 256 + tid] = 0;
    }
}

// ---------------- counting sort of edge ids by dst ----------------
__global__ __launch_bounds__(256) void k_hist(const int* __restrict__ ei, int* __restrict__ hist) {
    const int t = blockIdx.x * 256 + threadIdx.x;
    atomicAdd(&hist[ei[E_TOTAL + t]], 1);
}

// single-block scan over NBINS = 1024*49 (replaces 3-kernel chain with serial middle)
__global__ __launch_bounds__(1024)
void k_scan(const int* __restrict__ hist, int* __restrict__ cursor) {
    __shared__ int s[1024];
    const int t = threadIdx.x;
    const int base = t * 49;
    int sum = 0;
    #pragma unroll
    for (int i = 0; i < 49; ++i) sum += hist[base + i];
    s[t] = sum;
    __syncthreads();
    for (int off = 1; off < 1024; off <<= 1) {
        int v = (t >= off) ? s[t - off] : 0;
        __syncthreads();
        s[t] += v;
        __syncthreads();
    }
    int run = s[t] - sum;   // exclusive prefix of this thread's chunk
    #pragma unroll
    for (int i = 0; i < 49; ++i) {
        cursor[base + i] = run;
        run += hist[base + i];
    }
}

__global__ __launch_bounds__(256)
void k_scatter(const int* __restrict__ ei, int* __restrict__ cursor, int* __restrict__ perm) {
    const int t = blockIdx.x * 256 + threadIdx.x;
    const int dst = ei[E_TOTAL + t];
    const int pos = atomicAdd(&cursor[dst], 1);
    perm[pos] = t;
}

// ================= MFMA kernels =================
constexpr int XK = 296;  // 288 + 8 pad
constexpr int HK = 136;  // 128 + 8 pad
constexpr int NK = 264;  // 256 + 8 pad
constexpr int FJ = 132;  // fp32 epilogue tile stride

// ---- pipelined sorted edge kernel: grid-stride tiles, register prefetch ----
__global__ __launch_bounds__(256, 4)
void edge_mfma_pipe(const unsigned short* __restrict__ hbf,
                    const int* __restrict__ ei,
                    const float* __restrict__ ea,
                    const int* __restrict__ perm,
                    const unsigned short* __restrict__ W1t,  // [128][288]
                    const float* __restrict__ b1,
                    const unsigned short* __restrict__ W2t,  // [128][128]
                    const float* __restrict__ b2,
                    float* __restrict__ mi)
{
    __shared__ alignas(16) unsigned short sA[32 * XK];       // 18.9 KB gathered input
    __shared__ alignas(16) unsigned char  sR2[32 * FJ * 4];  // 16.9 KB union {sH bf16 | sF fp32}
    __shared__ int sDst[32];

    unsigned short* sH = (unsigned short*)sR2;
    float*          sF = (float*)sR2;

    const int tid  = threadIdx.x;
    const int lane = tid & 63;
    const int w    = tid >> 6;
    const int q    = lane >> 4;
    const int lr   = lane & 15;
    const int n0   = w * 32;

    const int e  = tid >> 3;   // edge slot 0..31 (8 threads per edge)
    const int c0 = tid & 7;    // chunk lane

    const short8* hbf8 = (const short8*)hbf;
    const float4* ea4  = (const float4*)ea;

    const int NTILE  = E_TOTAL / 32;   // 25000
    const int stride = gridDim.x;

    const float bias1[2] = { b1[n0 + lr], b1[n0 + 16 + lr] };
    const float bias2[2] = { b2[n0 + lr], b2[n0 + 16 + lr] };

    // prologue: prefetch first tile into registers
    short8 r0, r1, r2, r3; float4 rea; int rd;
    int t = blockIdx.x;
    if (t < NTILE) {
        const int p = perm[t * 32 + e];
        const int s = ei[p];
        rd          = ei[E_TOTAL + p];
        r0 = hbf8[(size_t)s * 16 + c0];
        r1 = hbf8[(size_t)s * 16 + c0 + 8];
        r2 = hbf8[(size_t)rd * 16 + c0];
        r3 = hbf8[(size_t)rd * 16 + c0 + 8];
        rea = ea4[(size_t)p * 8 + c0];
    }

    for (; t < NTILE; t += stride) {
        __syncthreads();   // (A) prev iter's sF reads done; sA free for rewrite

        // ---- store current tile regs -> LDS ----
        *(short8*)&sA[e * XK + c0 * 8]        = r0;
        *(short8*)&sA[e * XK + (c0 + 8) * 8]  = r1;
        *(short8*)&sA[e * XK + (c0 + 16) * 8] = r2;
        *(short8*)&sA[e * XK + (c0 + 24) * 8] = r3;
        {
            unsigned short* pe = &sA[e * XK + 256 + c0 * 4];
            pe[0] = f2bf(rea.x); pe[1] = f2bf(rea.y);
            pe[2] = f2bf(rea.z); pe[3] = f2bf(rea.w);
        }
        if (c0 == 0) sDst[e] = rd;

        // ---- issue prefetch for tile t+stride (hidden behind GEMMs) ----
        const int tn = t + stride;
        if (tn < NTILE) {
            const int p = perm[tn * 32 + e];
            const int s = ei[p];
            rd          = ei[E_TOTAL + p];
            r0 = hbf8[(size_t)s * 16 + c0];
            r1 = hbf8[(size_t)s * 16 + c0 + 8];
            r2 = hbf8[(size_t)rd * 16 + c0];
            r3 = hbf8[(size_t)rd * 16 + c0 + 8];
            rea = ea4[(size_t)p * 8 + c0];
        }

        __syncthreads();   // (B) sA + sDst ready

        // ---- GEMM1: [32 x 288] @ [288 x 128] ----
        floatx4 acc[2][2];
        #pragma unroll
        for (int mt = 0; mt < 2; ++mt)
            #pragma unroll
            for (int nt = 0; nt < 2; ++nt)
                acc[mt][nt] = (floatx4){0.f, 0.f, 0.f, 0.f};

        #pragma unroll
        for (int ks = 0; ks < 9; ++ks) {
            const int kb = ks * 32 + q * 8;
            short8 a[2], b[2];
            #pragma unroll
            for (int mt = 0; mt < 2; ++mt)
                a[mt] = *(const short8*)(&sA[(mt * 16 + lr) * XK + kb]);
            #pragma unroll
            for (int nt = 0; nt < 2; ++nt)
                b[nt] = *(const short8*)(&W1t[(n0 + nt * 16 + lr) * 288 + kb]);
            #pragma unroll
            for (int mt = 0; mt < 2; ++mt)
                #pragma unroll
                for (int nt = 0; nt < 2; ++nt)
                    acc[mt][nt] = __builtin_amdgcn_mfma_f32_16x16x32_bf16(
                        a[mt], b[nt], acc[mt][nt], 0, 0, 0);
        }

        // relu + bias -> sH (region2; free since barrier A)
        #pragma unroll
        for (int mt = 0; mt < 2; ++mt)
            #pragma unroll
            for (int nt = 0; nt < 2; ++nt)
                #pragma unroll
                for (int r = 0; r < 4; ++r) {
                    float v = fmaxf(acc[mt][nt][r] + bias1[nt], 0.f);
                    sH[(mt * 16 + q * 4 + r) * HK + n0 + nt * 16 + lr] = f2bf(v);
                }
        __syncthreads();   // (C) sH ready

        // ---- GEMM2: [32 x 128] @ [128 x 128] ----
        floatx4 acc2[2][2];
        #pragma unroll
        for (int mt = 0; mt < 2; ++mt)
            #pragma unroll
            for (int nt = 0; nt < 2; ++nt)
                acc2[mt][nt] = (floatx4){0.f, 0.f, 0.f, 0.f};

        #pragma unroll
        for (int ks = 0; ks < 4; ++ks) {
            const int kb = ks * 32 + q * 8;
            short8 a[2], b[2];
            #pragma unroll
            for (int mt = 0; mt < 2; ++mt)
                a[mt] = *(const short8*)(&sH[(mt * 16 + lr) * HK + kb]);
            #pragma unroll
            for (int nt = 0; nt < 2; ++nt)
                b[nt] = *(const short8*)(&W2t[(n0 + nt * 16 + lr) * 128 + kb]);
            #pragma unroll
            for (int mt = 0; mt < 2; ++mt)
                #pragma unroll
                for (int nt = 0; nt < 2; ++nt)
                    acc2[mt][nt] = __builtin_amdgcn_mfma_f32_16x16x32_bf16(
                        a[mt], b[nt], acc2[mt][nt], 0, 0, 0);
        }
        __syncthreads();   // (D) GEMM2 done reading sH before sF overwrite

        // ---- m_ij tile -> sF (fp32) ----
        #pragma unroll
        for (int mt = 0; mt < 2; ++mt)
            #pragma unroll
            for (int nt = 0; nt < 2; ++nt)
                #pragma unroll
                for (int r = 0; r < 4; ++r)
                    sF[(mt * 16 + q * 4 + r) * FJ + n0 + nt * 16 + lr] =
                        acc2[mt][nt][r] + bias2[nt];
        __syncthreads();   // (E) sF ready

        // ---- run-length-reduced scatter (dst-sorted) ----
        if (tid < 128) {
            const int j = tid;
            float sum = 0.f;
            for (int r = 0; r < 32; ++r) {
                sum += sF[r * FJ + j];
                const int dst = sDst[r];
                if (r == 31 || sDst[r + 1] != dst) {
                    atomicAdd(&mi[(size_t)dst * 128 + j], sum);
                    sum = 0.f;
                }
            }
        }
    }
}

// ---- flat fallback edge kernel ----
template <bool PRECVT>
__global__ __launch_bounds__(256, 8)
void edge_mfma_flat(const float* __restrict__ h,
                    const unsigned short* __restrict__ hbf,
                    const int* __restrict__ ei,
                    const float* __restrict__ ea,
                    const unsigned short* __restrict__ W1t,
                    const float* __restrict__ b1,
                    const unsigned short* __restrict__ W2t,
                    const float* __restrict__ b2,
                    float* __restrict__ mi)
{
    __shared__ unsigned short sMem[32 * XK];
    __shared__ int sDst[32];

    const int tid = threadIdx.x;
    const int e0  = blockIdx.x * 32;
    if (tid < 32) sDst[tid] = ei[E_TOTAL + e0 + tid];

    const float4* h4   = (const float4*)h;
    const short8* hbf8 = (const short8*)hbf;
    const float4* ea4  = (const float4*)ea;
    #pragma unroll
    for (int it = 0; it < 5; ++it) {
        const int idx = tid + it * 256;
        const int e  = idx / 40;
        const int c  = idx - e * 40;
        const int ge = e0 + e;
        if (c < 32) {
            const int node = (c < 16) ? ei[ge] : ei[E_TOTAL + ge];
            const int cc = c & 15;
            short8 v;
            if (PRECVT) {
                v = hbf8[(size_t)node * 16 + cc];
            } else {
                float4 x = h4[(size_t)node * 32 + cc * 2];
                float4 y = h4[(size_t)node * 32 + cc * 2 + 1];
                v = (short8){ (short)f2bf(x.x), (short)f2bf(x.y), (short)f2bf(x.z), (short)f2bf(x.w),
                              (short)f2bf(y.x), (short)f2bf(y.y), (short)f2bf(y.z), (short)f2bf(y.w) };
            }
            *(short8*)(&sMem[e * XK + c * 8]) = v;
        } else {
            float4 x = ea4[(size_t)ge * 8 + (c - 32)];
            unsigned short* p = &sMem[e * XK + 128 + c * 4];
            p[0] = f2bf(x.x); p[1] = f2bf(x.y); p[2] = f2bf(x.z); p[3] = f2bf(x.w);
        }
    }
    __syncthreads();

    const int lane = tid & 63;
    const int w    = tid >> 6;
    const int q    = lane >> 4;
    const int lr   = lane & 15;
    const int n0   = w * 32;

    floatx4 acc[2][2];
    #pragma unroll
    for (int mt = 0; mt < 2; ++mt)
        #pragma unroll
        for (int nt = 0; nt < 2; ++nt)
            acc[mt][nt] = (floatx4){0.f, 0.f, 0.f, 0.f};
    #pragma unroll
    for (int ks = 0; ks < 9; ++ks) {
        const int kb = ks * 32 + q * 8;
        short8 a[2], b[2];
        #pragma unroll
        for (int mt = 0; mt < 2; ++mt)
            a[mt] = *(const short8*)(&sMem[(mt * 16 + lr) * XK + kb]);
        #pragma unroll
        for (int nt = 0; nt < 2; ++nt)
            b[nt] = *(const short8*)(&W1t[(n0 + nt * 16 + lr) * 288 + kb]);
        #pragma unroll
        for (int mt = 0; mt < 2; ++mt)
            #pragma unroll
            for (int nt = 0; nt < 2; ++nt)
                acc[mt][nt] = __builtin_amdgcn_mfma_f32_16x16x32_bf16(
                    a[mt], b[nt], acc[mt][nt], 0, 0, 0);
    }
    __syncthreads();
    {
        float bias[2] = { b1[n0 + lr], b1[n0 + 16 + lr] };
        #pragma unroll
        for (int mt = 0; mt < 2; ++mt)
            #pragma unroll
            for (int nt = 0; nt < 2; ++nt)
                #pragma unroll
                for (int r = 0; r < 4; ++r) {
                    float v = fmaxf(acc[mt][nt][r] + bias[nt], 0.f);
                    sMem[(mt * 16 + q * 4 + r) * HK + n0 + nt * 16 + lr] = f2bf(v);
                }
    }
    __syncthreads();
    floatx4 acc2[2][2];
    #pragma unroll
    for (int mt = 0; mt < 2; ++mt)
        #pragma unroll
        for (int nt = 0; nt < 2; ++nt)
            acc2[mt][nt] = (floatx4){0.f, 0.f, 0.f, 0.f};
    #pragma unroll
    for (int ks = 0; ks < 4; ++ks) {
        const int kb = ks * 32 + q * 8;
        short8 a[2], b[2];
        #pragma unroll
        for (int mt = 0; mt < 2; ++mt)
            a[mt] = *(const short8*)(&sMem[(mt * 16 + lr) * HK + kb]);
        #pragma unroll
        for (int nt = 0; nt < 2; ++nt)
            b[nt] = *(const short8*)(&W2t[(n0 + nt * 16 + lr) * 128 + kb]);
        #pragma unroll
        for (int mt = 0; mt < 2; ++mt)
            #pragma unroll
            for (int nt = 0; nt < 2; ++nt)
                acc2[mt][nt] = __builtin_amdgcn_mfma_f32_16x16x32_bf16(
                    a[mt], b[nt], acc2[mt][nt], 0, 0, 0);
    }
    {
        float bias[2] = { b2[n0 + lr], b2[n0 + 16 + lr] };
        #pragma unroll
        for (int mt = 0; mt < 2; ++mt)
            #pragma unroll
            for (int r = 0; r < 4; ++r) {
                const int m   = mt * 16 + q * 4 + r;
                const int dst = sDst[m];
                float* row = &mi[(size_t)dst * 128];
                #pragma unroll
                for (int nt = 0; nt < 2; ++nt)
                    atomicAdd(&row[n0 + nt * 16 + lr], acc2[mt][nt][r] + bias[nt]);
            }
    }
}

// ---- node kernel ----
__global__ __launch_bounds__(256, 8)
void node_mfma(const float* __restrict__ h,
               const float* __restrict__ mi,
               const unsigned short* __restrict__ W1t,
               const float* __restrict__ b1,
               const unsigned short* __restrict__ W2t,
               const float* __restrict__ b2,
               float* __restrict__ out)
{
    __shared__ unsigned short sMem[32 * NK];

    const int tid = threadIdx.x;
    const int g0  = blockIdx.x * 32;

    const float4* h4  = (const float4*)h;
    const float4* mi4 = (const float4*)mi;
    #pragma unroll
    for (int it = 0; it < 8; ++it) {
        const int idx = tid + it * 256;
        const int n  = idx >> 6;
        const int c  = idx & 63;
        const int gn = g0 + n;
        float4 v = make_float4(0.f, 0.f, 0.f, 0.f);
        if (gn < N_TOTAL)
            v = (c < 32) ? h4[(size_t)gn * 32 + c] : mi4[(size_t)gn * 32 + (c - 32)];
        unsigned short* p = &sMem[n * NK + c * 4];
        p[0] = f2bf(v.x); p[1] = f2bf(v.y); p[2] = f2bf(v.z); p[3] = f2bf(v.w);
    }
    __syncthreads();

    const int lane = tid & 63;
    const int w    = tid >> 6;
    const int q    = lane >> 4;
    const int lr   = lane & 15;
    const int n0   = w * 32;

    floatx4 acc[2][2];
    #pragma unroll
    for (int mt = 0; mt < 2; ++mt)
        #pragma unroll
        for (int nt = 0; nt < 2; ++nt)
            acc[mt][nt] = (floatx4){0.f, 0.f, 0.f, 0.f};
    #pragma unroll
    for (int ks = 0; ks < 8; ++ks) {
        const int kb = ks * 32 + q * 8;
        short8 a[2], b[2];
        #pragma unroll
        for (int mt = 0; mt < 2; ++mt)
            a[mt] = *(const short8*)(&sMem[(mt * 16 + lr) * NK + kb]);
        #pragma unroll
        for (int nt = 0; nt < 2; ++nt)
            b[nt] = *(const short8*)(&W1t[(n0 + nt * 16 + lr) * 256 + kb]);
        #pragma unroll
        for (int mt = 0; mt < 2; ++mt)
            #pragma unroll
            for (int nt = 0; nt < 2; ++nt)
                acc[mt][nt] = __builtin_amdgcn_mfma_f32_16x16x32_bf16(
                    a[mt], b[nt], acc[mt][nt], 0, 0, 0);
    }
    __syncthreads();
    {
        float bias[2] = { b1[n0 + lr], b1[n0 + 16 + lr] };
        #pragma unroll
        for (int mt = 0; mt < 2; ++mt)
            #pragma unroll
            for (int nt = 0; nt < 2; ++nt)
                #pragma unroll
                for (int r = 0; r < 4; ++r) {
                    float v = fmaxf(acc[mt][nt][r] + bias[nt], 0.f);
                    sMem[(mt * 16 + q * 4 + r) * HK + n0 + nt * 16 + lr] = f2bf(v);
                }
    }
    __syncthreads();
    floatx4 acc2[2][2];
    #pragma unroll
    for (int mt = 0; mt < 2; ++mt)
        #pragma unroll
        for (int nt = 0; nt < 2; ++nt)
            acc2[mt][nt] = (floatx4){0.f, 0.f, 0.f, 0.f};
    #pragma unroll
    for (int ks = 0; ks < 4; ++ks) {
        const int kb = ks * 32 + q * 8;
        short8 a[2], b[2];
        #pragma unroll
        for (int mt = 0; mt < 2; ++mt)
            a[mt] = *(const short8*)(&sMem[(mt * 16 + lr) * HK + kb]);
        #pragma unroll
        for (int nt = 0; nt < 2; ++nt)
            b[nt] = *(const short8*)(&W2t[(n0 + nt * 16 + lr) * 128 + kb]);
        #pragma unroll
        for (int mt = 0; mt < 2; ++mt)
            #pragma unroll
            for (int nt = 0; nt < 2; ++nt)
                acc2[mt][nt] = __builtin_amdgcn_mfma_f32_16x16x32_bf16(
                    a[mt], b[nt], acc2[mt][nt], 0, 0, 0);
    }
    {
        float bias[2] = { b2[n0 + lr], b2[n0 + 16 + lr] };
        #pragma unroll
        for (int mt = 0; mt < 2; ++mt)
            #pragma unroll
            for (int r = 0; r < 4; ++r) {
                const int gm = g0 + mt * 16 + q * 4 + r;
                if (gm < N_TOTAL) {
                    #pragma unroll
                    for (int nt = 0; nt < 2; ++nt)
                        out[(size_t)gm * 128 + n0 + nt * 16 + lr] =
                            acc2[mt][nt][r] + bias[nt];
                }
            }
    }
}

extern "C" void kernel_launch(void* const* d_in, const int* in_sizes, int n_in,
                              void* d_out, int out_size, void* d_ws, size_t ws_size,
                              hipStream_t stream) {
    const float* h   = (const float*)d_in[0];
    const int*   ei  = (const int*)d_in[1];
    const float* ea  = (const float*)d_in[2];
    const float* We1 = (const float*)d_in[3];
    const float* be1 = (const float*)d_in[4];
    const float* We2 = (const float*)d_in[5];
    const float* be2 = (const float*)d_in[6];
    const float* Wh1 = (const float*)d_in[7];
    const float* bh1 = (const float*)d_in[8];
    const float* Wh2 = (const float*)d_in[9];
    const float* bh2 = (const float*)d_in[10];
    float* out = (float*)d_out;

    const size_t szMi   = (size_t)N_TOTAL * 128 * sizeof(float);
    const size_t szW1t  = 128 * 288 * 2;
    const size_t szW2t  = 128 * 128 * 2;
    const size_t szWh1t = 128 * 256 * 2;
    const size_t szWh2t = 128 * 128 * 2;
    const size_t szHbf  = (size_t)N_TOTAL * 128 * 2;
    const size_t szPerm = (size_t)E_TOTAL * 4;
    const size_t szHist = (size_t)NBINS * 4;

    const size_t offW1t  = szMi;
    const size_t offW2t  = offW1t + szW1t;
    const size_t offWh1t = offW2t + szW2t;
    const size_t offWh2t = offWh1t + szWh1t;
    const size_t offHbf  = offWh2t + szWh2t;
    const size_t offPerm = offHbf + szHbf;
    const size_t offHist = offPerm + szPerm;
    const size_t offCur  = offHist + szHist;
    const size_t needFull = offCur + szHist;
    const size_t needCvt  = offPerm;

    char* wsb = (char*)d_ws;
    float* mi = (float*)wsb;
    unsigned short* W1t  = (unsigned short*)(wsb + offW1t);
    unsigned short* W2t  = (unsigned short*)(wsb + offW2t);
    unsigned short* Wh1t = (unsigned short*)(wsb + offWh1t);
    unsigned short* Wh2t = (unsigned short*)(wsb + offWh2t);
    unsigned short* hbf  = (unsigned short*)(wsb + offHbf);
    int* perm    = (int*)(wsb + offPerm);
    int* hist    = (int*)(wsb + offHist);
    int* cursor  = (int*)(wsb + offCur);

    const int full = (ws_size >= needFull) ? 1 : 0;

    prep<<<9971, 256, 0, stream>>>(We1, We2, Wh1, Wh2, W1t, W2t, Wh1t, Wh2t,
                                   h, hbf, full, mi, hist);

    if (full) {
        k_hist<<<E_TOTAL / 256, 256, 0, stream>>>(ei, hist);
        k_scan<<<1, 1024, 0, stream>>>(hist, cursor);
        k_scatter<<<E_TOTAL / 256, 256, 0, stream>>>(ei, cursor, perm);
        edge_mfma_pipe<<<2560, 256, 0, stream>>>(
            hbf, ei, ea, perm, W1t, be1, W2t, be2, mi);
    } else if (ws_size >= needCvt + szHbf) {
        edge_mfma_flat<true><<<E_TOTAL / 32, 256, 0, stream>>>(
            h, hbf, ei, ea, W1t, be1, W2t, be2, mi);
    } else {
        edge_mfma_flat<false><<<E_TOTAL / 32, 256, 0, stream>>>(
            h, nullptr, ei, ea, W1t, be1, W2t, be2, mi);
    }
    node_mfma<<<(N_TOTAL + 31) / 32, 256, 0, stream>>>(
        h, mi, Wh1t, bh1, Wh2t, bh2, out);
    (void)in_sizes; (void)n_in; (void)out_size;
}